// Round 2
// 633.709 us; speedup vs baseline: 1.1056x; 1.1056x over previous
//
#include <hip/hip_runtime.h>
#include <stdint.h>

#define M_TOK 4096
#define K_IN  4096
#define N_OUT 11008
#define GROUPS 64
#define WPR 512            // packed words per weight row = K_IN/8

// ---- 256x256 8-phase GEMM geometry ----
#define BM 256
#define BN 256
#define BK 64
#define TM (M_TOK / BM)    // 16
#define TN (N_OUT / BN)    // 43
#define NWG (TM * TN)      // 688  (688 % 8 == 0 -> simple bijective XCD swizzle)
#define KTILES (K_IN / BK) // 64

typedef __bf16 bf16x8 __attribute__((ext_vector_type(8)));
typedef float  f32x4  __attribute__((ext_vector_type(4)));

__device__ __forceinline__ uint16_t f2bf(float f) {
  uint32_t u = __float_as_uint(f);
  u += 0x7FFFu + ((u >> 16) & 1u);
  return (uint16_t)(u >> 16);
}

// ---------------------------------------------------------------------------
// Fused preprocessing (unchanged): blocks [0, XBLK) convert x fp32->bf16,
// blocks [XBLK, XBLK+WBLK) dequantize int4 W -> bf16.
// ---------------------------------------------------------------------------
#define XBLK ((M_TOK * K_IN) / (256 * 8))        // 8192
#define WBLK ((N_OUT * WPR) / 256)               // 22016

__global__ __launch_bounds__(256) void prep(const float* __restrict__ x,
                                            const uint32_t* __restrict__ qw,
                                            const uint32_t* __restrict__ qz,
                                            const float* __restrict__ sc,
                                            uint16_t* __restrict__ xb,
                                            uint16_t* __restrict__ wb) {
  if (blockIdx.x < XBLK) {
    size_t i = ((size_t)blockIdx.x * 256 + threadIdx.x) * 8;
    const float4* p = (const float4*)(x + i);
    float4 a = p[0];
    float4 b = p[1];
    uint4 v;
    v.x = (uint32_t)f2bf(a.x) | ((uint32_t)f2bf(a.y) << 16);
    v.y = (uint32_t)f2bf(a.z) | ((uint32_t)f2bf(a.w) << 16);
    v.z = (uint32_t)f2bf(b.x) | ((uint32_t)f2bf(b.y) << 16);
    v.w = (uint32_t)f2bf(b.z) | ((uint32_t)f2bf(b.w) << 16);
    *(uint4*)(xb + i) = v;
  } else {
    int idx = (blockIdx.x - XBLK) * 256 + threadIdx.x;  // word index
    int o = idx >> 9;
    int p = idx & 511;
    int g = p >> 3;
    uint32_t zw = qz[o * (GROUPS / 8) + (g >> 3)];
    float zp = (float)((zw >> ((g & 7) * 4)) & 15u);
    float s = sc[o * GROUPS + g];
    float c = -s * zp;
    uint32_t w = qw[idx];
    uint4 v;
    uint32_t r[4];
#pragma unroll
    for (int j = 0; j < 4; j++) {
      float f0 = (float)((w >> (8 * j)) & 15u);
      float f1 = (float)((w >> (8 * j + 4)) & 15u);
      r[j] = (uint32_t)f2bf(fmaf(f0, s, c)) | ((uint32_t)f2bf(fmaf(f1, s, c)) << 16);
    }
    v.x = r[0]; v.y = r[1]; v.z = r[2]; v.w = r[3];
    *(uint4*)(wb + (size_t)idx * 8) = v;
  }
}

// ---------------------------------------------------------------------------
// 256x256x64 8-phase bf16 GEMM (T2+T3+T4+T5), resubmission with rule-#18
// hardening: sched_barrier(0) immediately after every lgkmcnt(0) wait.
//
// A (MxK rm) * B^T (NxK rm) + bias. 512 threads = 8 waves (2M x 4N).
// Per wave: C block 128x64 = acc[8][4] f32x4. LDS 128 KiB, double-buffered.
//
// Per iteration: 2 K-tiles (buf0 then buf1), 8 phases. Each phase:
//   {ds_read one subtile ; issue one half-tile global_load_lds ; s_barrier ;
//    lgkmcnt(0) ; sched_barrier(0) ; setprio(1) ; 16 MFMA ; setprio(0) ;
//    s_barrier ; sched_barrier(0)}
// vmcnt(4) ONLY at the ends of ph3/ph7: 2 half-tiles (4 loads/wave) stay in
// flight across barriers - never drained to 0 in the main loop.
//
// Hazard ledger (verified):
//   consume: ph0 A0h0+B0h0 | ph1 A0h0+B0h1 | ph2 A0h1+B0h1 | ph3 A0h1+B0h0
//            ph4..7 same on buf1.
//   stage:   ph0 buf1.A.h1<-kt+1 | ph1 buf1.B.h0<-kt+1
//            ph2 buf0.A.h0<-kt+2 | ph3 buf0.B.h1<-kt+2
//            ph4 buf0.A.h1<-kt+2 | ph5 buf0.B.h0<-kt+2
//            ph6 buf1.A.h0<-kt+3 | ph7 buf1.B.h1<-kt+3
//   Every stage target's last reader closed >=1 barrier before the issue.
//   vmcnt(4)@ph3 retires prev-ph6,7+ph0,1 => all kt+1 landed before ph4.
//   vmcnt(4)@ph7 retires ph2..5          => all kt+2 landed before next ph0.
// LDS swizzle: LDS[row][c] = global chunk (c ^ (row&7)) via pre-swizzled
// global source (global_load_lds dest stays linear); reads use kc^(row&7).
// ---------------------------------------------------------------------------
#define SBAR()   __builtin_amdgcn_s_barrier()
#define SCHED0() __builtin_amdgcn_sched_barrier(0)
#define WAITV(n) asm volatile("s_waitcnt vmcnt(" #n ")" ::: "memory")
#define WAITL0() asm volatile("s_waitcnt lgkmcnt(0)" ::: "memory")

#define STAGE_A(buf, half, kt) do {                                            \
  _Pragma("unroll")                                                            \
  for (int c_ = 0; c_ < 2; c_++) {                                             \
    const int r_ = (half) * 128 + c_ * 64 + wave * 8;                          \
    __builtin_amdgcn_global_load_lds(                                          \
        (const __attribute__((address_space(1))) uint32_t*)(                   \
            gA + (size_t)r_ * K_IN + (size_t)(kt) * BK),                       \
        (__attribute__((address_space(3))) uint32_t*)(&As[(buf)][r_][0]),      \
        16, 0, 0);                                                             \
  } } while (0)

#define STAGE_B(buf, half, kt) do {                                            \
  _Pragma("unroll")                                                            \
  for (int c_ = 0; c_ < 2; c_++) {                                             \
    const int r_ = (half) * 128 + c_ * 64 + wave * 8;                          \
    __builtin_amdgcn_global_load_lds(                                          \
        (const __attribute__((address_space(1))) uint32_t*)(                   \
            gB + (size_t)r_ * K_IN + (size_t)(kt) * BK),                       \
        (__attribute__((address_space(3))) uint32_t*)(&Bs[(buf)][r_][0]),      \
        16, 0, 0);                                                             \
  } } while (0)

#define LOAD_A(buf, mh) do {                                                   \
  _Pragma("unroll")                                                            \
  for (int i2_ = 0; i2_ < 4; i2_++) {                                          \
    const int row_ = (mh) * 128 + wm * 64 + i2_ * 16 + col;                    \
    af[i2_][0] = *(const bf16x8*)&As[(buf)][row_][(quad ^ cs) << 3];           \
    af[i2_][1] = *(const bf16x8*)&As[(buf)][row_][((4 + quad) ^ cs) << 3];     \
  } } while (0)

#define LOAD_B(buf, nh) do {                                                   \
  _Pragma("unroll")                                                            \
  for (int j2_ = 0; j2_ < 2; j2_++) {                                          \
    const int row_ = (nh) * 128 + wn * 32 + j2_ * 16 + col;                    \
    bfr[j2_][0] = *(const bf16x8*)&Bs[(buf)][row_][(quad ^ cs) << 3];          \
    bfr[j2_][1] = *(const bf16x8*)&Bs[(buf)][row_][((4 + quad) ^ cs) << 3];    \
  } } while (0)

#define MMA(mh, nh) do {                                                       \
  __builtin_amdgcn_s_setprio(1);                                               \
  _Pragma("unroll")                                                            \
  for (int i2_ = 0; i2_ < 4; i2_++)                                            \
    _Pragma("unroll")                                                          \
    for (int j2_ = 0; j2_ < 2; j2_++) {                                        \
      acc[(mh)*4 + i2_][(nh)*2 + j2_] = __builtin_amdgcn_mfma_f32_16x16x32_bf16( \
          af[i2_][0], bfr[j2_][0], acc[(mh)*4 + i2_][(nh)*2 + j2_], 0, 0, 0);  \
      acc[(mh)*4 + i2_][(nh)*2 + j2_] = __builtin_amdgcn_mfma_f32_16x16x32_bf16( \
          af[i2_][1], bfr[j2_][1], acc[(mh)*4 + i2_][(nh)*2 + j2_], 0, 0, 0);  \
    }                                                                          \
  __builtin_amdgcn_s_setprio(0); } while (0)

__global__ __launch_bounds__(512, 2) void gemm_bf16(const uint16_t* __restrict__ A,
                                                    const uint16_t* __restrict__ B,
                                                    const float* __restrict__ bias,
                                                    float* __restrict__ C) {
  __shared__ __align__(16) uint16_t As[2][BM][BK];   // 64 KiB
  __shared__ __align__(16) uint16_t Bs[2][BN][BK];   // 64 KiB

  // bijective XCD swizzle (NWG % 8 == 0), then mt-major: each XCD works 2
  // consecutive A panels (4 MiB -> its L2); B streams through L3.
  const int bid = blockIdx.x;
  const int wg  = (bid & 7) * (NWG / 8) + (bid >> 3);
  const int mt  = wg / TN;
  const int nt  = wg % TN;
  const size_t m0 = (size_t)mt * BM;
  const size_t n0 = (size_t)nt * BN;

  const int tid  = threadIdx.x;
  const int wave = tid >> 6;
  const int lane = tid & 63;
  const int wm   = wave >> 2;          // 0..1
  const int wn   = wave & 3;           // 0..3
  const int lrow = lane >> 3;          // 0..7  (stage row within 8-row stripe)
  const int lcol = lane & 7;           // 0..7  (stage 16B chunk)
  const int col  = lane & 15;          // MFMA frag row/col within 16
  const int quad = lane >> 4;          // 0..3
  const int cs   = col & 7;            // read-side swizzle key (= row&7)

  // pre-swizzled global bases: lane (lrow,lcol) fetches chunk (lcol^lrow) so
  // the linear global_load_lds dest realizes LDS[row][c] = g[row][c^(row&7)]
  const uint16_t* gA = A + (m0 + lrow) * K_IN + (size_t)((lcol ^ lrow) << 3);
  const uint16_t* gB = B + (n0 + lrow) * K_IN + (size_t)((lcol ^ lrow) << 3);

  f32x4 acc[8][4];
#pragma unroll
  for (int i = 0; i < 8; i++)
#pragma unroll
    for (int j = 0; j < 4; j++)
      acc[i][j] = (f32x4){0.f, 0.f, 0.f, 0.f};

  bf16x8 af[4][2];    // A frags: 4 row-frags x 2 k-slices (one M-half)
  bf16x8 bfr[2][2];   // B frags: 2 col-frags x 2 k-slices (one N-half)

  // ---- prologue: kt0 fully + kt1 {A.h0, B.h1}; keep kt1's 2 halves in flight
  STAGE_A(0, 0, 0); STAGE_B(0, 1, 0); STAGE_A(0, 1, 0); STAGE_B(0, 0, 0);
  STAGE_A(1, 0, 1); STAGE_B(1, 1, 1);
  WAITV(4);
  SBAR(); SCHED0();

  for (int it = 0; it < KTILES / 2 - 1; ++it) {
    const int kt = 2 * it;
    // phase 0: kt(buf0) M0N0 ; stage buf1.A.h1 <- kt+1
    LOAD_A(0, 0); LOAD_B(0, 0);
    STAGE_A(1, 1, kt + 1);
    SBAR(); WAITL0(); SCHED0();
    MMA(0, 0);
    SBAR(); SCHED0();
    // phase 1: M0N1 ; stage buf1.B.h0 <- kt+1
    LOAD_B(0, 1);
    STAGE_B(1, 0, kt + 1);
    SBAR(); WAITL0(); SCHED0();
    MMA(0, 1);
    SBAR(); SCHED0();
    // phase 2: M1N1 ; stage buf0.A.h0 <- kt+2
    LOAD_A(0, 1);
    STAGE_A(0, 0, kt + 2);
    SBAR(); WAITL0(); SCHED0();
    MMA(1, 1);
    SBAR(); SCHED0();
    // phase 3: M1N0 ; stage buf0.B.h1 <- kt+2 ; boundary vmcnt(4)
    LOAD_B(0, 0);
    STAGE_B(0, 1, kt + 2);
    SBAR(); WAITL0(); SCHED0();
    MMA(1, 0);
    WAITV(4);
    SBAR(); SCHED0();
    // phase 4: kt+1(buf1) M0N0 ; stage buf0.A.h1 <- kt+2
    LOAD_A(1, 0); LOAD_B(1, 0);
    STAGE_A(0, 1, kt + 2);
    SBAR(); WAITL0(); SCHED0();
    MMA(0, 0);
    SBAR(); SCHED0();
    // phase 5: M0N1 ; stage buf0.B.h0 <- kt+2
    LOAD_B(1, 1);
    STAGE_B(0, 0, kt + 2);
    SBAR(); WAITL0(); SCHED0();
    MMA(0, 1);
    SBAR(); SCHED0();
    // phase 6: M1N1 ; stage buf1.A.h0 <- kt+3
    LOAD_A(1, 1);
    STAGE_A(1, 0, kt + 3);
    SBAR(); WAITL0(); SCHED0();
    MMA(1, 1);
    SBAR(); SCHED0();
    // phase 7: M1N0 ; stage buf1.B.h1 <- kt+3 ; boundary vmcnt(4)
    LOAD_B(1, 0);
    STAGE_B(1, 1, kt + 3);
    SBAR(); WAITL0(); SCHED0();
    MMA(1, 0);
    WAITV(4);
    SBAR(); SCHED0();
  }

  // ---- epilogue iteration: kt = 62 (buf0), 63 (buf1); finish kt63 staging
  LOAD_A(0, 0); LOAD_B(0, 0);
  STAGE_A(1, 1, KTILES - 1);
  SBAR(); WAITL0(); SCHED0();
  MMA(0, 0);
  SBAR(); SCHED0();
  LOAD_B(0, 1);
  STAGE_B(1, 0, KTILES - 1);
  SBAR(); WAITL0(); SCHED0();
  MMA(0, 1);
  SBAR(); SCHED0();
  LOAD_A(0, 1);
  SBAR(); WAITL0(); SCHED0();
  MMA(1, 1);
  SBAR(); SCHED0();
  LOAD_B(0, 0);
  SBAR(); WAITL0(); SCHED0();
  MMA(1, 0);
  WAITV(0);
  SBAR(); SCHED0();
  LOAD_A(1, 0); LOAD_B(1, 0);
  SBAR(); WAITL0(); SCHED0();
  MMA(0, 0);
  SBAR(); SCHED0();
  LOAD_B(1, 1);
  SBAR(); WAITL0(); SCHED0();
  MMA(0, 1);
  SBAR(); SCHED0();
  LOAD_A(1, 1);
  SBAR(); WAITL0(); SCHED0();
  MMA(1, 1);
  SBAR(); SCHED0();
  LOAD_B(1, 0);
  SBAR(); WAITL0(); SCHED0();
  MMA(1, 0);

  // ---- C write: D row = quad*4 + r, col = lane&15 within each 16x16 frag
#pragma unroll
  for (int i = 0; i < 8; i++) {
    const int mrow = (int)m0 + (i >> 2) * 128 + wm * 64 + (i & 3) * 16 + quad * 4;
#pragma unroll
    for (int j = 0; j < 4; j++) {
      const int ncol = (int)n0 + (j >> 1) * 128 + wn * 32 + (j & 1) * 16 + col;
      const float bv = bias[ncol];
      float* out = C + (size_t)mrow * N_OUT + ncol;
#pragma unroll
      for (int r = 0; r < 4; r++)
        __builtin_nontemporal_store(acc[i][j][r] + bv, out + (size_t)r * N_OUT);
    }
  }
}

// ---------------------------------------------------------------------------
// Fallback (ws too small): correct but slow fused kernel.
// ---------------------------------------------------------------------------
__global__ __launch_bounds__(256) void fallback_fused(const float* __restrict__ x,
                                                      const uint32_t* __restrict__ qw,
                                                      const uint32_t* __restrict__ qz,
                                                      const float* __restrict__ sc,
                                                      const float* __restrict__ bias,
                                                      float* __restrict__ out) {
  __shared__ float xs[K_IN];
  const int t = blockIdx.y;
  const int o = blockIdx.x * 256 + threadIdx.x;
  for (int i = threadIdx.x; i < K_IN; i += 256) xs[i] = x[(size_t)t * K_IN + i];
  __syncthreads();
  float acc = 0.f;
  const uint32_t* qwr = qw + (size_t)o * WPR;
  for (int g = 0; g < GROUPS; g++) {
    uint32_t zw = qz[o * (GROUPS / 8) + (g >> 3)];
    float zp = (float)((zw >> ((g & 7) * 4)) & 15u);
    float s = sc[o * GROUPS + g];
    float gacc = 0.f, gsum = 0.f;
    for (int w = 0; w < 8; w++) {
      uint32_t wv = qwr[g * 8 + w];
#pragma unroll
      for (int j = 0; j < 8; j++) {
        float xv = xs[g * 64 + w * 8 + j];
        gacc = fmaf((float)((wv >> (4 * j)) & 15u), xv, gacc);
        gsum += xv;
      }
    }
    acc += s * (gacc - zp * gsum);
  }
  out[(size_t)t * N_OUT + o] = acc + bias[o];
}

// ---------------------------------------------------------------------------
extern "C" void kernel_launch(void* const* d_in, const int* in_sizes, int n_in,
                              void* d_out, int out_size, void* d_ws, size_t ws_size,
                              hipStream_t stream) {
  (void)in_sizes; (void)n_in; (void)out_size;
  const float*    x    = (const float*)d_in[0];
  const uint32_t* qw   = (const uint32_t*)d_in[1];
  const uint32_t* qz   = (const uint32_t*)d_in[2];
  const float*    sc   = (const float*)d_in[3];
  const float*    bias = (const float*)d_in[4];
  float* out = (float*)d_out;

  const size_t xb_bytes = (size_t)M_TOK * K_IN * 2;
  const size_t wb_bytes = (size_t)N_OUT * K_IN * 2;

  if (ws_size >= xb_bytes + wb_bytes) {
    uint16_t* xb = (uint16_t*)d_ws;
    uint16_t* wb = (uint16_t*)((char*)d_ws + xb_bytes);
    prep<<<XBLK + WBLK, 256, 0, stream>>>(x, qw, qz, sc, xb, wb);
    gemm_bf16<<<NWG, 512, 0, stream>>>(xb, wb, bias, out);
  } else {
    fallback_fused<<<dim3(N_OUT / 256, M_TOK), 256, 0, stream>>>(x, qw, qz, sc, bias, out);
  }
}

// Round 3
// 579.265 us; speedup vs baseline: 1.2095x; 1.0940x over previous
//
#include <hip/hip_runtime.h>
#include <stdint.h>

#define M_TOK 4096
#define K_IN  4096
#define N_OUT 11008
#define GROUPS 64
#define WPR 512            // packed words per weight row = K_IN/8

// ---- 256x256 8-phase GEMM geometry ----
#define BM 256
#define BN 256
#define BK 64
#define TM (M_TOK / BM)    // 16
#define TN (N_OUT / BN)    // 43
#define NWG (TM * TN)      // 688  (688 % 8 == 0 -> simple bijective XCD swizzle)
#define KTILES (K_IN / BK) // 64

typedef __bf16 bf16x8 __attribute__((ext_vector_type(8)));
typedef float  f32x4  __attribute__((ext_vector_type(4)));

__device__ __forceinline__ uint16_t f2bf(float f) {
  uint32_t u = __float_as_uint(f);
  u += 0x7FFFu + ((u >> 16) & 1u);
  return (uint16_t)(u >> 16);
}

// ---------------------------------------------------------------------------
// Fused preprocessing: blocks [0, XBLK) convert x fp32->bf16 (8 elem/thread),
// blocks [XBLK, XBLK+WBLK) dequantize int4 W -> bf16, 4 words/thread strided
// by 128 words within the row so every load/store instruction is fully
// coalesced (lane-consecutive).
// ---------------------------------------------------------------------------
#define XBLK ((M_TOK * K_IN) / (256 * 8))        // 8192
#define WBLK ((N_OUT * WPR) / (256 * 4))         // 5504

__global__ __launch_bounds__(256) void prep(const float* __restrict__ x,
                                            const uint32_t* __restrict__ qw,
                                            const uint32_t* __restrict__ qz,
                                            const float* __restrict__ sc,
                                            uint16_t* __restrict__ xb,
                                            uint16_t* __restrict__ wb) {
  if (blockIdx.x < XBLK) {
    size_t i = ((size_t)blockIdx.x * 256 + threadIdx.x) * 8;
    const float4* p = (const float4*)(x + i);
    float4 a = p[0];
    float4 b = p[1];
    uint4 v;
    v.x = (uint32_t)f2bf(a.x) | ((uint32_t)f2bf(a.y) << 16);
    v.y = (uint32_t)f2bf(a.z) | ((uint32_t)f2bf(a.w) << 16);
    v.z = (uint32_t)f2bf(b.x) | ((uint32_t)f2bf(b.y) << 16);
    v.w = (uint32_t)f2bf(b.z) | ((uint32_t)f2bf(b.w) << 16);
    *(uint4*)(xb + i) = v;
  } else {
    // t in [0, N_OUT*WPR/4): row o = t/128, base word p0 = t%128; this thread
    // handles words p0 + j*128, j=0..3 (same row, 4 distinct groups).
    int t = (blockIdx.x - XBLK) * 256 + threadIdx.x;
    int o  = t >> 7;
    int p0 = t & 127;
    const uint32_t* qwr = qw + (size_t)o * WPR + p0;
    uint16_t* wbr = wb + ((size_t)o * WPR + p0) * 8;
#pragma unroll
    for (int j = 0; j < 4; j++) {
      int p = p0 + j * 128;
      int g = p >> 3;
      uint32_t zw = qz[o * (GROUPS / 8) + (g >> 3)];
      float zp = (float)((zw >> ((g & 7) * 4)) & 15u);
      float s = sc[o * GROUPS + g];
      float c = -s * zp;
      uint32_t w = qwr[j * 128];
      uint4 v;
      uint32_t r[4];
#pragma unroll
      for (int q = 0; q < 4; q++) {
        float f0 = (float)((w >> (8 * q)) & 15u);
        float f1 = (float)((w >> (8 * q + 4)) & 15u);
        r[q] = (uint32_t)f2bf(fmaf(f0, s, c)) | ((uint32_t)f2bf(fmaf(f1, s, c)) << 16);
      }
      v.x = r[0]; v.y = r[1]; v.z = r[2]; v.w = r[3];
      *(uint4*)(wbr + (size_t)j * 128 * 8) = v;
    }
  }
}

// ---------------------------------------------------------------------------
// 256x256x64 8-phase bf16 GEMM (T2+T3+T4+T5), deepened pipeline (round 3).
//
// Consume order (A-frag reuse, per K-tile): ph0 M0N0, ph1 M0N1, ph2 M1N1,
// ph3 M1N0; ph4-7 same on buf1. Halves freed: Ah0@1, Bh1@2, {Ah1,Bh0}@3
// (+4 for buf1). First-needed next K-tile: {Ah0,Bh0}@0, Bh1@1, Ah1@2.
//
// Stage schedule (each target free >=1 barrier before issue; FIFO ledger
// below; 2 loads/thread per stage):
//   ph0: buf1.Bh0<-kt+1   ph1: buf1.Ah1<-kt+1
//   ph2: buf0.Ah0<-kt+2   ph3: buf0.Bh1<-kt+2
//   ph4: buf0.Bh0<-kt+2   ph5: buf0.Ah1<-kt+2
//   ph6: buf1.Ah0<-kt+3   ph7: buf1.Bh1<-kt+3
// Waits (after MMA, before closing barrier):
//   end-ph1 vmcnt(8): outstanding {p5,p6,p7,0,1}=10 -> retires p5 (buf0.Ah1,
//     needed ph2).
//   end-ph3 vmcnt(6): outstanding {p6,p7,0,1,2,3}=12 -> retires p6,p7,ph0
//     (buf1.Ah0/Bh1/Bh0, needed ph4/ph5/ph4).
//   end-ph5 vmcnt(8): outstanding {1,2,3,4,5}=10 -> retires ph1 (buf1.Ah1,
//     needed ph6).
//   end-ph7 vmcnt(6): outstanding {2..7}=12 -> retires ph2,3,4 (buf0.Ah0/Bh1/
//     Bh0, needed next ph0/ph1/ph0).
// Every stage gets 3-5 phases of latency budget; >=6 loads stay in flight at
// every wait point (was 4 / 2-phase budget in round 2 -> 35% MfmaUtil).
// LDS swizzle: LDS[row][c] = global chunk (c ^ (row&7)) via pre-swizzled
// global source (global_load_lds dest stays linear); reads use kc^(row&7).
// ---------------------------------------------------------------------------
#define SBAR()   __builtin_amdgcn_s_barrier()
#define SCHED0() __builtin_amdgcn_sched_barrier(0)
#define WAITV(n) asm volatile("s_waitcnt vmcnt(" #n ")" ::: "memory")
#define WAITL0() asm volatile("s_waitcnt lgkmcnt(0)" ::: "memory")

#define STAGE_A(buf, half, kt) do {                                            \
  _Pragma("unroll")                                                            \
  for (int c_ = 0; c_ < 2; c_++) {                                             \
    const int r_ = (half) * 128 + c_ * 64 + wave * 8;                          \
    __builtin_amdgcn_global_load_lds(                                          \
        (const __attribute__((address_space(1))) uint32_t*)(                   \
            gA + (size_t)r_ * K_IN + (size_t)(kt) * BK),                       \
        (__attribute__((address_space(3))) uint32_t*)(&As[(buf)][r_][0]),      \
        16, 0, 0);                                                             \
  } } while (0)

#define STAGE_B(buf, half, kt) do {                                            \
  _Pragma("unroll")                                                            \
  for (int c_ = 0; c_ < 2; c_++) {                                             \
    const int r_ = (half) * 128 + c_ * 64 + wave * 8;                          \
    __builtin_amdgcn_global_load_lds(                                          \
        (const __attribute__((address_space(1))) uint32_t*)(                   \
            gB + (size_t)r_ * K_IN + (size_t)(kt) * BK),                       \
        (__attribute__((address_space(3))) uint32_t*)(&Bs[(buf)][r_][0]),      \
        16, 0, 0);                                                             \
  } } while (0)

#define LOAD_A(buf, mh) do {                                                   \
  _Pragma("unroll")                                                            \
  for (int i2_ = 0; i2_ < 4; i2_++) {                                          \
    const int row_ = (mh) * 128 + wm * 64 + i2_ * 16 + col;                    \
    af[i2_][0] = *(const bf16x8*)&As[(buf)][row_][(quad ^ cs) << 3];           \
    af[i2_][1] = *(const bf16x8*)&As[(buf)][row_][((4 + quad) ^ cs) << 3];     \
  } } while (0)

#define LOAD_B(buf, nh) do {                                                   \
  _Pragma("unroll")                                                            \
  for (int j2_ = 0; j2_ < 2; j2_++) {                                          \
    const int row_ = (nh) * 128 + wn * 32 + j2_ * 16 + col;                    \
    bfr[j2_][0] = *(const bf16x8*)&Bs[(buf)][row_][(quad ^ cs) << 3];          \
    bfr[j2_][1] = *(const bf16x8*)&Bs[(buf)][row_][((4 + quad) ^ cs) << 3];    \
  } } while (0)

#define MMA(mh, nh) do {                                                       \
  __builtin_amdgcn_s_setprio(1);                                               \
  _Pragma("unroll")                                                            \
  for (int i2_ = 0; i2_ < 4; i2_++)                                            \
    _Pragma("unroll")                                                          \
    for (int j2_ = 0; j2_ < 2; j2_++) {                                        \
      acc[(mh)*4 + i2_][(nh)*2 + j2_] = __builtin_amdgcn_mfma_f32_16x16x32_bf16( \
          af[i2_][0], bfr[j2_][0], acc[(mh)*4 + i2_][(nh)*2 + j2_], 0, 0, 0);  \
      acc[(mh)*4 + i2_][(nh)*2 + j2_] = __builtin_amdgcn_mfma_f32_16x16x32_bf16( \
          af[i2_][1], bfr[j2_][1], acc[(mh)*4 + i2_][(nh)*2 + j2_], 0, 0, 0);  \
    }                                                                          \
  __builtin_amdgcn_s_setprio(0); } while (0)

__global__ __launch_bounds__(512, 2) void gemm_bf16(const uint16_t* __restrict__ A,
                                                    const uint16_t* __restrict__ B,
                                                    const float* __restrict__ bias,
                                                    float* __restrict__ C) {
  __shared__ __align__(16) uint16_t As[2][BM][BK];   // 64 KiB
  __shared__ __align__(16) uint16_t Bs[2][BN][BK];   // 64 KiB

  // bijective XCD swizzle (NWG % 8 == 0), then mt-major: each XCD works 2
  // consecutive A panels (4 MiB -> its L2); B streams through L3.
  const int bid = blockIdx.x;
  const int wg  = (bid & 7) * (NWG / 8) + (bid >> 3);
  const int mt  = wg / TN;
  const int nt  = wg % TN;
  const size_t m0 = (size_t)mt * BM;
  const size_t n0 = (size_t)nt * BN;

  const int tid  = threadIdx.x;
  const int wave = tid >> 6;
  const int lane = tid & 63;
  const int wm   = wave >> 2;          // 0..1
  const int wn   = wave & 3;           // 0..3
  const int lrow = lane >> 3;          // 0..7  (stage row within 8-row stripe)
  const int lcol = lane & 7;           // 0..7  (stage 16B chunk)
  const int col  = lane & 15;          // MFMA frag row/col within 16
  const int quad = lane >> 4;          // 0..3
  const int cs   = col & 7;            // read-side swizzle key (= row&7)

  // pre-swizzled global bases: lane (lrow,lcol) fetches chunk (lcol^lrow) so
  // the linear global_load_lds dest realizes LDS[row][c] = g[row][c^(row&7)]
  const uint16_t* gA = A + (m0 + lrow) * K_IN + (size_t)((lcol ^ lrow) << 3);
  const uint16_t* gB = B + (n0 + lrow) * K_IN + (size_t)((lcol ^ lrow) << 3);

  f32x4 acc[8][4];
#pragma unroll
  for (int i = 0; i < 8; i++)
#pragma unroll
    for (int j = 0; j < 4; j++)
      acc[i][j] = (f32x4){0.f, 0.f, 0.f, 0.f};

  bf16x8 af[4][2];    // A frags: 4 row-frags x 2 k-slices (one M-half)
  bf16x8 bfr[2][2];   // B frags: 2 col-frags x 2 k-slices (one N-half)

  // ---- prologue: buf0 <- kt0 (order Ah0,Bh1,Bh0,Ah1), buf1.{Ah0,Bh1} <- kt1.
  // WAITV(6) retires the first 3 stages; in-flight = {buf0.Ah1, buf1.Ah0,
  // buf1.Bh1} = steady-state entry {p5,p6,p7}.
  STAGE_A(0, 0, 0); STAGE_B(0, 1, 0); STAGE_B(0, 0, 0); STAGE_A(0, 1, 0);
  STAGE_A(1, 0, 1); STAGE_B(1, 1, 1);
  WAITV(6);
  SBAR(); SCHED0();

  for (int it = 0; it < KTILES / 2 - 1; ++it) {
    const int kt = 2 * it;
    // phase 0: buf0 M0N0 ; stage buf1.Bh0 <- kt+1
    LOAD_A(0, 0); LOAD_B(0, 0);
    STAGE_B(1, 0, kt + 1);
    SBAR(); WAITL0(); SCHED0();
    MMA(0, 0);
    SBAR(); SCHED0();
    // phase 1: M0N1 ; stage buf1.Ah1 <- kt+1 ; vmcnt(8)
    LOAD_B(0, 1);
    STAGE_A(1, 1, kt + 1);
    SBAR(); WAITL0(); SCHED0();
    MMA(0, 1);
    WAITV(8);
    SBAR(); SCHED0();
    // phase 2: M1N1 ; stage buf0.Ah0 <- kt+2
    LOAD_A(0, 1);
    STAGE_A(0, 0, kt + 2);
    SBAR(); WAITL0(); SCHED0();
    MMA(1, 1);
    SBAR(); SCHED0();
    // phase 3: M1N0 ; stage buf0.Bh1 <- kt+2 ; vmcnt(6)
    LOAD_B(0, 0);
    STAGE_B(0, 1, kt + 2);
    SBAR(); WAITL0(); SCHED0();
    MMA(1, 0);
    WAITV(6);
    SBAR(); SCHED0();
    // phase 4: buf1 M0N0 ; stage buf0.Bh0 <- kt+2
    LOAD_A(1, 0); LOAD_B(1, 0);
    STAGE_B(0, 0, kt + 2);
    SBAR(); WAITL0(); SCHED0();
    MMA(0, 0);
    SBAR(); SCHED0();
    // phase 5: M0N1 ; stage buf0.Ah1 <- kt+2 ; vmcnt(8)
    LOAD_B(1, 1);
    STAGE_A(0, 1, kt + 2);
    SBAR(); WAITL0(); SCHED0();
    MMA(0, 1);
    WAITV(8);
    SBAR(); SCHED0();
    // phase 6: M1N1 ; stage buf1.Ah0 <- kt+3
    LOAD_A(1, 1);
    STAGE_A(1, 0, kt + 3);
    SBAR(); WAITL0(); SCHED0();
    MMA(1, 1);
    SBAR(); SCHED0();
    // phase 7: M1N0 ; stage buf1.Bh1 <- kt+3 ; vmcnt(6)
    LOAD_B(1, 0);
    STAGE_B(1, 1, kt + 3);
    SBAR(); WAITL0(); SCHED0();
    MMA(1, 0);
    WAITV(6);
    SBAR(); SCHED0();
  }

  // ---- epilogue iteration: kt = 62 (buf0), 63 (buf1).
  // Stages only ph0/ph1 (buf1.Bh0/Ah1 <- 63); waits: vmcnt(8)@ph1 (retires
  // prev5 = buf0.Ah1), vmcnt(2)@ph3 (retires prev6,prev7,e0), vmcnt(0)@ph5.
  LOAD_A(0, 0); LOAD_B(0, 0);
  STAGE_B(1, 0, KTILES - 1);
  SBAR(); WAITL0(); SCHED0();
  MMA(0, 0);
  SBAR(); SCHED0();
  LOAD_B(0, 1);
  STAGE_A(1, 1, KTILES - 1);
  SBAR(); WAITL0(); SCHED0();
  MMA(0, 1);
  WAITV(8);
  SBAR(); SCHED0();
  LOAD_A(0, 1);
  SBAR(); WAITL0(); SCHED0();
  MMA(1, 1);
  SBAR(); SCHED0();
  LOAD_B(0, 0);
  SBAR(); WAITL0(); SCHED0();
  MMA(1, 0);
  WAITV(2);
  SBAR(); SCHED0();
  LOAD_A(1, 0); LOAD_B(1, 0);
  SBAR(); WAITL0(); SCHED0();
  MMA(0, 0);
  SBAR(); SCHED0();
  LOAD_B(1, 1);
  SBAR(); WAITL0(); SCHED0();
  MMA(0, 1);
  WAITV(0);
  SBAR(); SCHED0();
  LOAD_A(1, 1);
  SBAR(); WAITL0(); SCHED0();
  MMA(1, 1);
  SBAR(); SCHED0();
  LOAD_B(1, 0);
  SBAR(); WAITL0(); SCHED0();
  MMA(1, 0);

  // ---- C write: D row = quad*4 + r, col = lane&15 within each 16x16 frag
#pragma unroll
  for (int i = 0; i < 8; i++) {
    const int mrow = (int)m0 + (i >> 2) * 128 + wm * 64 + (i & 3) * 16 + quad * 4;
#pragma unroll
    for (int j = 0; j < 4; j++) {
      const int ncol = (int)n0 + (j >> 1) * 128 + wn * 32 + (j & 1) * 16 + col;
      const float bv = bias[ncol];
      float* out = C + (size_t)mrow * N_OUT + ncol;
#pragma unroll
      for (int r = 0; r < 4; r++)
        __builtin_nontemporal_store(acc[i][j][r] + bv, out + (size_t)r * N_OUT);
    }
  }
}

// ---------------------------------------------------------------------------
// Fallback (ws too small): correct but slow fused kernel.
// ---------------------------------------------------------------------------
__global__ __launch_bounds__(256) void fallback_fused(const float* __restrict__ x,
                                                      const uint32_t* __restrict__ qw,
                                                      const uint32_t* __restrict__ qz,
                                                      const float* __restrict__ sc,
                                                      const float* __restrict__ bias,
                                                      float* __restrict__ out) {
  __shared__ float xs[K_IN];
  const int t = blockIdx.y;
  const int o = blockIdx.x * 256 + threadIdx.x;
  for (int i = threadIdx.x; i < K_IN; i += 256) xs[i] = x[(size_t)t * K_IN + i];
  __syncthreads();
  float acc = 0.f;
  const uint32_t* qwr = qw + (size_t)o * WPR;
  for (int g = 0; g < GROUPS; g++) {
    uint32_t zw = qz[o * (GROUPS / 8) + (g >> 3)];
    float zp = (float)((zw >> ((g & 7) * 4)) & 15u);
    float s = sc[o * GROUPS + g];
    float gacc = 0.f, gsum = 0.f;
    for (int w = 0; w < 8; w++) {
      uint32_t wv = qwr[g * 8 + w];
#pragma unroll
      for (int j = 0; j < 8; j++) {
        float xv = xs[g * 64 + w * 8 + j];
        gacc = fmaf((float)((wv >> (4 * j)) & 15u), xv, gacc);
        gsum += xv;
      }
    }
    acc += s * (gacc - zp * gsum);
  }
  out[(size_t)t * N_OUT + o] = acc + bias[o];
}

// ---------------------------------------------------------------------------
extern "C" void kernel_launch(void* const* d_in, const int* in_sizes, int n_in,
                              void* d_out, int out_size, void* d_ws, size_t ws_size,
                              hipStream_t stream) {
  (void)in_sizes; (void)n_in; (void)out_size;
  const float*    x    = (const float*)d_in[0];
  const uint32_t* qw   = (const uint32_t*)d_in[1];
  const uint32_t* qz   = (const uint32_t*)d_in[2];
  const float*    sc   = (const float*)d_in[3];
  const float*    bias = (const float*)d_in[4];
  float* out = (float*)d_out;

  const size_t xb_bytes = (size_t)M_TOK * K_IN * 2;
  const size_t wb_bytes = (size_t)N_OUT * K_IN * 2;

  if (ws_size >= xb_bytes + wb_bytes) {
    uint16_t* xb = (uint16_t*)d_ws;
    uint16_t* wb = (uint16_t*)((char*)d_ws + xb_bytes);
    prep<<<XBLK + WBLK, 256, 0, stream>>>(x, qw, qz, sc, xb, wb);
    gemm_bf16<<<NWG, 512, 0, stream>>>(xb, wb, bias, out);
  } else {
    fallback_fused<<<dim3(N_OUT / 256, M_TOK), 256, 0, stream>>>(x, qw, qz, sc, bias, out);
  }
}

// Round 4
// 579.058 us; speedup vs baseline: 1.2099x; 1.0004x over previous
//
#include <hip/hip_runtime.h>
#include <stdint.h>

#define M_TOK 4096
#define K_IN  4096
#define N_OUT 11008
#define GROUPS 64
#define WPR 512            // packed words per weight row = K_IN/8

// ---- 256x256 8-phase GEMM geometry ----
#define BM 256
#define BN 256
#define BK 64
#define TM (M_TOK / BM)    // 16
#define TN (N_OUT / BN)    // 43
#define NWG (TM * TN)      // 688  (688 % 8 == 0 -> simple bijective XCD swizzle)
#define KTILES (K_IN / BK) // 64

typedef __bf16 bf16x8 __attribute__((ext_vector_type(8)));
typedef float  f32x4  __attribute__((ext_vector_type(4)));

__device__ __forceinline__ uint16_t f2bf(float f) {
  uint32_t u = __float_as_uint(f);
  u += 0x7FFFu + ((u >> 16) & 1u);
  return (uint16_t)(u >> 16);
}

// ---------------------------------------------------------------------------
// Fused preprocessing (unchanged from round 3).
// ---------------------------------------------------------------------------
#define XBLK ((M_TOK * K_IN) / (256 * 8))        // 8192
#define WBLK ((N_OUT * WPR) / (256 * 4))         // 5504

__global__ __launch_bounds__(256) void prep(const float* __restrict__ x,
                                            const uint32_t* __restrict__ qw,
                                            const uint32_t* __restrict__ qz,
                                            const float* __restrict__ sc,
                                            uint16_t* __restrict__ xb,
                                            uint16_t* __restrict__ wb) {
  if (blockIdx.x < XBLK) {
    size_t i = ((size_t)blockIdx.x * 256 + threadIdx.x) * 8;
    const float4* p = (const float4*)(x + i);
    float4 a = p[0];
    float4 b = p[1];
    uint4 v;
    v.x = (uint32_t)f2bf(a.x) | ((uint32_t)f2bf(a.y) << 16);
    v.y = (uint32_t)f2bf(a.z) | ((uint32_t)f2bf(a.w) << 16);
    v.z = (uint32_t)f2bf(b.x) | ((uint32_t)f2bf(b.y) << 16);
    v.w = (uint32_t)f2bf(b.z) | ((uint32_t)f2bf(b.w) << 16);
    *(uint4*)(xb + i) = v;
  } else {
    int t = (blockIdx.x - XBLK) * 256 + threadIdx.x;
    int o  = t >> 7;
    int p0 = t & 127;
    const uint32_t* qwr = qw + (size_t)o * WPR + p0;
    uint16_t* wbr = wb + ((size_t)o * WPR + p0) * 8;
#pragma unroll
    for (int j = 0; j < 4; j++) {
      int p = p0 + j * 128;
      int g = p >> 3;
      uint32_t zw = qz[o * (GROUPS / 8) + (g >> 3)];
      float zp = (float)((zw >> ((g & 7) * 4)) & 15u);
      float s = sc[o * GROUPS + g];
      float c = -s * zp;
      uint32_t w = qwr[j * 128];
      uint4 v;
      uint32_t r[4];
#pragma unroll
      for (int q = 0; q < 4; q++) {
        float f0 = (float)((w >> (8 * q)) & 15u);
        float f1 = (float)((w >> (8 * q + 4)) & 15u);
        r[q] = (uint32_t)f2bf(fmaf(f0, s, c)) | ((uint32_t)f2bf(fmaf(f1, s, c)) << 16);
      }
      v.x = r[0]; v.y = r[1]; v.z = r[2]; v.w = r[3];
      *(uint4*)(wbr + (size_t)j * 128 * 8) = v;
    }
  }
}

// ---------------------------------------------------------------------------
// 256x256x64 8-phase bf16 GEMM, round 4: progressive LDS drain.
//
// Round-3 post-mortem: forced `lgkmcnt(0)+sched_barrier(0)` before every MMA
// serialized the full per-phase LDS drain (up to 12 ds_read_b128 x 8 waves
// sharing the LDS pipe) against the MFMA cluster -> 1360 cyc phases with only
// ~155 cyc of matrix work per SIMD (MfmaUtil 41%). The ds_reads are
// compiler-visible IR loads, so LLVM emits exact per-register counted
// lgkmcnt waits; removing the blanket drain lets MFMA issue as soon as its
// own fragments land, overlapping the rest of the drain with compute.
//
// Safety (unchanged invariant): every ds_read's result is consumed by an
// MFMA in the same phase (compiler inserts the wait before that MFMA), i.e.
// before the wave's closing barrier; every LDS region is overwritten >=1
// full phase after its last read phase. So cross-wave LDS handoff still
// holds without the explicit drain.
//
// vmcnt ledger (identical to round 3):
//   stages: ph0 b1.Bh0<-kt+1, ph1 b1.Ah1<-kt+1, ph2 b0.Ah0<-kt+2,
//           ph3 b0.Bh1<-kt+2, ph4 b0.Bh0<-kt+2, ph5 b0.Ah1<-kt+2,
//           ph6 b1.Ah0<-kt+3, ph7 b1.Bh1<-kt+3   (2 loads/thread each)
//   waits:  vmcnt(8)@ph1-end, vmcnt(6)@ph3-end, vmcnt(8)@ph5-end,
//           vmcnt(6)@ph7-end  (>=6 loads always in flight; 3-5 phase budget)
// LDS swizzle: LDS[row][c] = global chunk (c ^ (row&7)) via pre-swizzled
// global source (global_load_lds dest stays linear); reads use kc^(row&7).
// ---------------------------------------------------------------------------
#define SBAR()   __builtin_amdgcn_s_barrier()
#define SCHED0() __builtin_amdgcn_sched_barrier(0)
#define WAITV(n) asm volatile("s_waitcnt vmcnt(" #n ")" ::: "memory")

#define STAGE_A(buf, half, kt) do {                                            \
  _Pragma("unroll")                                                            \
  for (int c_ = 0; c_ < 2; c_++) {                                             \
    const int r_ = (half) * 128 + c_ * 64 + wave * 8;                          \
    __builtin_amdgcn_global_load_lds(                                          \
        (const __attribute__((address_space(1))) uint32_t*)(                   \
            gA + (size_t)r_ * K_IN + (size_t)(kt) * BK),                       \
        (__attribute__((address_space(3))) uint32_t*)(&As[(buf)][r_][0]),      \
        16, 0, 0);                                                             \
  } } while (0)

#define STAGE_B(buf, half, kt) do {                                            \
  _Pragma("unroll")                                                            \
  for (int c_ = 0; c_ < 2; c_++) {                                             \
    const int r_ = (half) * 128 + c_ * 64 + wave * 8;                          \
    __builtin_amdgcn_global_load_lds(                                          \
        (const __attribute__((address_space(1))) uint32_t*)(                   \
            gB + (size_t)r_ * K_IN + (size_t)(kt) * BK),                       \
        (__attribute__((address_space(3))) uint32_t*)(&Bs[(buf)][r_][0]),      \
        16, 0, 0);                                                             \
  } } while (0)

#define LOAD_A(buf, mh) do {                                                   \
  _Pragma("unroll")                                                            \
  for (int i2_ = 0; i2_ < 4; i2_++) {                                          \
    const int row_ = (mh) * 128 + wm * 64 + i2_ * 16 + col;                    \
    af[i2_][0] = *(const bf16x8*)&As[(buf)][row_][(quad ^ cs) << 3];           \
    af[i2_][1] = *(const bf16x8*)&As[(buf)][row_][((4 + quad) ^ cs) << 3];     \
  } } while (0)

#define LOAD_B(buf, nh) do {                                                   \
  _Pragma("unroll")                                                            \
  for (int j2_ = 0; j2_ < 2; j2_++) {                                          \
    const int row_ = (nh) * 128 + wn * 32 + j2_ * 16 + col;                    \
    bfr[j2_][0] = *(const bf16x8*)&Bs[(buf)][row_][(quad ^ cs) << 3];          \
    bfr[j2_][1] = *(const bf16x8*)&Bs[(buf)][row_][((4 + quad) ^ cs) << 3];    \
  } } while (0)

#define MMA(mh, nh) do {                                                       \
  __builtin_amdgcn_s_setprio(1);                                               \
  _Pragma("unroll")                                                            \
  for (int i2_ = 0; i2_ < 4; i2_++)                                            \
    _Pragma("unroll")                                                          \
    for (int j2_ = 0; j2_ < 2; j2_++) {                                        \
      acc[(mh)*4 + i2_][(nh)*2 + j2_] = __builtin_amdgcn_mfma_f32_16x16x32_bf16( \
          af[i2_][0], bfr[j2_][0], acc[(mh)*4 + i2_][(nh)*2 + j2_], 0, 0, 0);  \
      acc[(mh)*4 + i2_][(nh)*2 + j2_] = __builtin_amdgcn_mfma_f32_16x16x32_bf16( \
          af[i2_][1], bfr[j2_][1], acc[(mh)*4 + i2_][(nh)*2 + j2_], 0, 0, 0);  \
    }                                                                          \
  __builtin_amdgcn_s_setprio(0); } while (0)

__global__ __launch_bounds__(512, 2) void gemm_bf16(const uint16_t* __restrict__ A,
                                                    const uint16_t* __restrict__ B,
                                                    const float* __restrict__ bias,
                                                    float* __restrict__ C) {
  __shared__ __align__(16) uint16_t As[2][BM][BK];   // 64 KiB
  __shared__ __align__(16) uint16_t Bs[2][BN][BK];   // 64 KiB

  // bijective XCD swizzle (NWG % 8 == 0), then mt-major: each XCD works 2
  // consecutive A panels (4 MiB -> its L2); B streams through L3.
  const int bid = blockIdx.x;
  const int wg  = (bid & 7) * (NWG / 8) + (bid >> 3);
  const int mt  = wg / TN;
  const int nt  = wg % TN;
  const size_t m0 = (size_t)mt * BM;
  const size_t n0 = (size_t)nt * BN;

  const int tid  = threadIdx.x;
  const int wave = tid >> 6;
  const int lane = tid & 63;
  const int wm   = wave >> 2;          // 0..1
  const int wn   = wave & 3;           // 0..3
  const int lrow = lane >> 3;          // 0..7  (stage row within 8-row stripe)
  const int lcol = lane & 7;           // 0..7  (stage 16B chunk)
  const int col  = lane & 15;          // MFMA frag row/col within 16
  const int quad = lane >> 4;          // 0..3
  const int cs   = col & 7;            // read-side swizzle key (= row&7)

  // pre-swizzled global bases: lane (lrow,lcol) fetches chunk (lcol^lrow) so
  // the linear global_load_lds dest realizes LDS[row][c] = g[row][c^(row&7)]
  const uint16_t* gA = A + (m0 + lrow) * K_IN + (size_t)((lcol ^ lrow) << 3);
  const uint16_t* gB = B + (n0 + lrow) * K_IN + (size_t)((lcol ^ lrow) << 3);

  f32x4 acc[8][4];
#pragma unroll
  for (int i = 0; i < 8; i++)
#pragma unroll
    for (int j = 0; j < 4; j++)
      acc[i][j] = (f32x4){0.f, 0.f, 0.f, 0.f};

  bf16x8 af[4][2];    // A frags: 4 row-frags x 2 k-slices (one M-half)
  bf16x8 bfr[2][2];   // B frags: 2 col-frags x 2 k-slices (one N-half)

  // ---- prologue: buf0 <- kt0 (order Ah0,Bh1,Bh0,Ah1), buf1.{Ah0,Bh1} <- kt1.
  // WAITV(6) retires the first 3 stages; in-flight = {buf0.Ah1, buf1.Ah0,
  // buf1.Bh1} = steady-state entry {p5,p6,p7}.
  STAGE_A(0, 0, 0); STAGE_B(0, 1, 0); STAGE_B(0, 0, 0); STAGE_A(0, 1, 0);
  STAGE_A(1, 0, 1); STAGE_B(1, 1, 1);
  WAITV(6);
  SBAR(); SCHED0();

  for (int it = 0; it < KTILES / 2 - 1; ++it) {
    const int kt = 2 * it;
    // phase 0: buf0 M0N0 ; stage buf1.Bh0 <- kt+1
    LOAD_A(0, 0); LOAD_B(0, 0);
    STAGE_B(1, 0, kt + 1);
    SBAR();
    MMA(0, 0);
    SBAR(); SCHED0();
    // phase 1: M0N1 ; stage buf1.Ah1 <- kt+1 ; vmcnt(8)
    LOAD_B(0, 1);
    STAGE_A(1, 1, kt + 1);
    SBAR();
    MMA(0, 1);
    WAITV(8);
    SBAR(); SCHED0();
    // phase 2: M1N1 ; stage buf0.Ah0 <- kt+2
    LOAD_A(0, 1);
    STAGE_A(0, 0, kt + 2);
    SBAR();
    MMA(1, 1);
    SBAR(); SCHED0();
    // phase 3: M1N0 ; stage buf0.Bh1 <- kt+2 ; vmcnt(6)
    LOAD_B(0, 0);
    STAGE_B(0, 1, kt + 2);
    SBAR();
    MMA(1, 0);
    WAITV(6);
    SBAR(); SCHED0();
    // phase 4: buf1 M0N0 ; stage buf0.Bh0 <- kt+2
    LOAD_A(1, 0); LOAD_B(1, 0);
    STAGE_B(0, 0, kt + 2);
    SBAR();
    MMA(0, 0);
    SBAR(); SCHED0();
    // phase 5: M0N1 ; stage buf0.Ah1 <- kt+2 ; vmcnt(8)
    LOAD_B(1, 1);
    STAGE_A(0, 1, kt + 2);
    SBAR();
    MMA(0, 1);
    WAITV(8);
    SBAR(); SCHED0();
    // phase 6: M1N1 ; stage buf1.Ah0 <- kt+3
    LOAD_A(1, 1);
    STAGE_A(1, 0, kt + 3);
    SBAR();
    MMA(1, 1);
    SBAR(); SCHED0();
    // phase 7: M1N0 ; stage buf1.Bh1 <- kt+3 ; vmcnt(6)
    LOAD_B(1, 0);
    STAGE_B(1, 1, kt + 3);
    SBAR();
    MMA(1, 0);
    WAITV(6);
    SBAR(); SCHED0();
  }

  // ---- epilogue iteration: kt = 62 (buf0), 63 (buf1).
  LOAD_A(0, 0); LOAD_B(0, 0);
  STAGE_B(1, 0, KTILES - 1);
  SBAR();
  MMA(0, 0);
  SBAR(); SCHED0();
  LOAD_B(0, 1);
  STAGE_A(1, 1, KTILES - 1);
  SBAR();
  MMA(0, 1);
  WAITV(8);
  SBAR(); SCHED0();
  LOAD_A(0, 1);
  SBAR();
  MMA(1, 1);
  SBAR(); SCHED0();
  LOAD_B(0, 0);
  SBAR();
  MMA(1, 0);
  WAITV(2);
  SBAR(); SCHED0();
  LOAD_A(1, 0); LOAD_B(1, 0);
  SBAR();
  MMA(0, 0);
  SBAR(); SCHED0();
  LOAD_B(1, 1);
  SBAR();
  MMA(0, 1);
  WAITV(0);
  SBAR(); SCHED0();
  LOAD_A(1, 1);
  SBAR();
  MMA(1, 1);
  SBAR(); SCHED0();
  LOAD_B(1, 0);
  SBAR();
  MMA(1, 0);

  // ---- C write: D row = quad*4 + r, col = lane&15 within each 16x16 frag
#pragma unroll
  for (int i = 0; i < 8; i++) {
    const int mrow = (int)m0 + (i >> 2) * 128 + wm * 64 + (i & 3) * 16 + quad * 4;
#pragma unroll
    for (int j = 0; j < 4; j++) {
      const int ncol = (int)n0 + (j >> 1) * 128 + wn * 32 + (j & 1) * 16 + col;
      const float bv = bias[ncol];
      float* out = C + (size_t)mrow * N_OUT + ncol;
#pragma unroll
      for (int r = 0; r < 4; r++)
        __builtin_nontemporal_store(acc[i][j][r] + bv, out + (size_t)r * N_OUT);
    }
  }
}

// ---------------------------------------------------------------------------
// Fallback (ws too small): correct but slow fused kernel.
// ---------------------------------------------------------------------------
__global__ __launch_bounds__(256) void fallback_fused(const float* __restrict__ x,
                                                      const uint32_t* __restrict__ qw,
                                                      const uint32_t* __restrict__ qz,
                                                      const float* __restrict__ sc,
                                                      const float* __restrict__ bias,
                                                      float* __restrict__ out) {
  __shared__ float xs[K_IN];
  const int t = blockIdx.y;
  const int o = blockIdx.x * 256 + threadIdx.x;
  for (int i = threadIdx.x; i < K_IN; i += 256) xs[i] = x[(size_t)t * K_IN + i];
  __syncthreads();
  float acc = 0.f;
  const uint32_t* qwr = qw + (size_t)o * WPR;
  for (int g = 0; g < GROUPS; g++) {
    uint32_t zw = qz[o * (GROUPS / 8) + (g >> 3)];
    float zp = (float)((zw >> ((g & 7) * 4)) & 15u);
    float s = sc[o * GROUPS + g];
    float gacc = 0.f, gsum = 0.f;
    for (int w = 0; w < 8; w++) {
      uint32_t wv = qwr[g * 8 + w];
#pragma unroll
      for (int j = 0; j < 8; j++) {
        float xv = xs[g * 64 + w * 8 + j];
        gacc = fmaf((float)((wv >> (4 * j)) & 15u), xv, gacc);
        gsum += xv;
      }
    }
    acc += s * (gacc - zp * gsum);
  }
  out[(size_t)t * N_OUT + o] = acc + bias[o];
}

// ---------------------------------------------------------------------------
extern "C" void kernel_launch(void* const* d_in, const int* in_sizes, int n_in,
                              void* d_out, int out_size, void* d_ws, size_t ws_size,
                              hipStream_t stream) {
  (void)in_sizes; (void)n_in; (void)out_size;
  const float*    x    = (const float*)d_in[0];
  const uint32_t* qw   = (const uint32_t*)d_in[1];
  const uint32_t* qz   = (const uint32_t*)d_in[2];
  const float*    sc   = (const float*)d_in[3];
  const float*    bias = (const float*)d_in[4];
  float* out = (float*)d_out;

  const size_t xb_bytes = (size_t)M_TOK * K_IN * 2;
  const size_t wb_bytes = (size_t)N_OUT * K_IN * 2;

  if (ws_size >= xb_bytes + wb_bytes) {
    uint16_t* xb = (uint16_t*)d_ws;
    uint16_t* wb = (uint16_t*)((char*)d_ws + xb_bytes);
    prep<<<XBLK + WBLK, 256, 0, stream>>>(x, qw, qz, sc, xb, wb);
    gemm_bf16<<<NWG, 512, 0, stream>>>(xb, wb, bias, out);
  } else {
    fallback_fused<<<dim3(N_OUT / 256, M_TOK), 256, 0, stream>>>(x, qw, qz, sc, bias, out);
  }
}